// Round 10
// baseline (892.769 us; speedup 1.0000x reference)
//
#include <hip/hip_runtime.h>
#include <math.h>

#define N 150
#define NP 160            // padded: 4 workers × 40 cols, float4-aligned
#define QUART 40
#define QUADS 10          // QUART/4
#define BLOCK 640         // 10 waves; 4 workers per row (600 active)
#define ITERS 100
#define WARM 5
#define CONV_TOL 1e-6f    // renormalized-iterate convergence tolerance

#define PI_F 3.14159265358979323846f
#define TWO_PI_F 6.28318530717958647692f
#define EPS_F 1e-16f
// SINKHORN_EPS = 0.05 ; base-2 log domain: K = C/(eps*ln2)
#define EPSLN2 0.03465735902799726f
#define INV_EPSLN2 28.853900817779268f
#define NEGBIG -1e30f

#if __has_builtin(__builtin_amdgcn_exp2f)
#define FEXP2(x) __builtin_amdgcn_exp2f(x)
#else
#define FEXP2(x) exp2f(x)
#endif
#if __has_builtin(__builtin_amdgcn_logf)
#define FLOG2(x) __builtin_amdgcn_logf(x)
#else
#define FLOG2(x) log2f(x)
#endif
#if __has_builtin(__builtin_amdgcn_rcpf)
#define FRCP(x) __builtin_amdgcn_rcpf(x)
#else
#define FRCP(x) (1.0f / (x))
#endif

// packed 2×f32 lane for v_pk_fma_f32 / v_pk_mul_f32 / v_pk_add_f32 emission
typedef float f2 __attribute__((ext_vector_type(2)));
union F4P { float4 v; f2 h[2]; float f[4]; };

#if __has_builtin(__builtin_elementwise_max)
#define F2MAX(a, b) __builtin_elementwise_max((a), (b))
#else
__device__ __forceinline__ f2 f2max_fb(f2 a, f2 b) {
    f2 r; r[0] = fmaxf(a[0], b[0]); r[1] = fmaxf(a[1], b[1]); return r;
}
#define F2MAX(a, b) f2max_fb((a), (b))
#endif

// compile-time element access into the f2-packed K arrays
#define KU(e) Ku[(e) >> 1][(e) & 1]
#define KT(e) Kt[(e) >> 1][(e) & 1]

// ---- DPP helpers: VALU-pipe cross-lane, no LDS traffic ----
// 0xB1 quad_perm xor1 ; 0x4E quad_perm xor2
__device__ __forceinline__ float dpp_xor1(float x) {
    return __int_as_float(__builtin_amdgcn_update_dpp(
        0, __float_as_int(x), 0xB1, 0xF, 0xF, true));
}
__device__ __forceinline__ float dpp_xor2(float x) {
    return __int_as_float(__builtin_amdgcn_update_dpp(
        0, __float_as_int(x), 0x4E, 0xF, 0xF, true));
}
__device__ __forceinline__ float quad_sum(float x) {
    x += dpp_xor1(x); x += dpp_xor2(x); return x;
}
__device__ __forceinline__ float quad_max(float x) {
    x = fmaxf(x, dpp_xor1(x)); x = fmaxf(x, dpp_xor2(x)); return x;
}

__device__ __forceinline__ float blockReduceSum(float v, float* red) {
    for (int o = 32; o > 0; o >>= 1) v += __shfl_down(v, o, 64);
    const int lane = threadIdx.x & 63;
    const int wv = threadIdx.x >> 6;
    __syncthreads();
    if (lane == 0) red[wv] = v;
    __syncthreads();
    float s = 0.f;
    #pragma unroll
    for (int i = 0; i < BLOCK / 64; ++i) s += red[i];
    return s;
}

// 3-component fused block reduction (bit-identical per component)
__device__ __forceinline__ void blockReduceSum3(
    float& x, float& y, float& z, float* red)
{
    for (int o = 32; o > 0; o >>= 1) {
        x += __shfl_down(x, o, 64);
        y += __shfl_down(y, o, 64);
        z += __shfl_down(z, o, 64);
    }
    const int lane = threadIdx.x & 63;
    const int wv = threadIdx.x >> 6;
    __syncthreads();
    if (lane == 0) { red[wv] = x; red[wv + 16] = y; red[wv + 32] = z; }
    __syncthreads();
    float sx = 0.f, sy = 0.f, sz = 0.f;
    #pragma unroll
    for (int i = 0; i < BLOCK / 64; ++i) {
        sx += red[i]; sy += red[i + 16]; sz += red[i + 32];
    }
    x = sx; y = sy; z = sz;
}

__global__ __launch_bounds__(BLOCK, 2) void emd_kernel(
    const float* __restrict__ p_recons,
    const float* __restrict__ p_target,
    float* __restrict__ out)
{
    __shared__ float xeta[N], xphi[N], yeta[N], yphi[N];
    __shared__ float l2a[N], l2b[N];
    __shared__ __align__(16) float uu[NP];
    __shared__ __align__(16) float vv[NP];
    __shared__ float red[48];

    const int b = blockIdx.x;
    const int tid = threadIdx.x;

    // ---- coordinate transform (both clouds) ----
    for (int c = 0; c < 2; ++c) {
        const float* P = (c == 0 ? p_recons : p_target) + (size_t)b * (N * 3);
        float px = 0.f, py = 0.f, pz = 0.f;
        if (tid < N) {
            px = P[tid * 3 + 0];
            py = P[tid * 3 + 1];
            pz = P[tid * 3 + 2];
        }
        float jx = px, jy = py, jz = pz;
        blockReduceSum3(jx, jy, jz, red);
        const float jpt  = sqrtf(jx * jx + jy * jy + EPS_F);
        const float jphi = atan2f(jy + EPS_F, jx + EPS_F);
        const float jeta = asinhf(jz / (jpt + EPS_F));

        float ptrel = 0.f, erel = 0.f, prel = 0.f;
        if (tid < N) {
            const float pt  = sqrtf(px * px + py * py + EPS_F);
            const float phi = atan2f(py + EPS_F, px + EPS_F);
            const float eta = asinhf(pz / (pt + EPS_F));
            erel = eta - jeta;
            float d = phi - jphi + PI_F;
            d = fmodf(d, TWO_PI_F);            // JAX % is floor-mod
            if (d < 0.f) d += TWO_PI_F;
            prel = d - PI_F;
            ptrel = pt / (jpt + EPS_F);
        }
        const float spt = blockReduceSum(ptrel, red);
        if (tid < N) {
            const float aa = ptrel / (spt + EPS_F);
            if (c == 0) { xeta[tid] = erel; xphi[tid] = prel; l2a[tid] = FLOG2(aa + EPS_F); }
            else        { yeta[tid] = erel; yphi[tid] = prel; l2b[tid] = FLOG2(aa + EPS_F); }
        }
    }
    __syncthreads();

    // ---- register-resident -K slices (log2 domain): 4 workers/row, 40 cols ----
    const int r = (tid >> 2) < N ? (tid >> 2) : (N - 1);   // clamped for uniform exec
    const int q = tid & 3;
    const bool writer = (q == 0) && ((tid >> 2) < N);
    const bool act = (tid >> 2) < N;

    f2 Ku[QUART / 2];   // log: -K[r][q*40+s] ; after fold: linear Ku'
    f2 Kt[QUART / 2];   // log: -K[q*40+s][r] ; after fold: linear Kt'
    {
        const float xe = xeta[r], xp = xphi[r];
        const float ye = yeta[r], yp = yphi[r];
        #pragma unroll
        for (int s = 0; s < QUART; ++s) {
            const int j = q * QUART + s;
            float ku = NEGBIG, kt = NEGBIG;       // pads never contribute
            if (j < N) {
                float de = xe - yeta[j], dp = xp - yphi[j];
                ku = -sqrtf(de * de + dp * dp + EPS_F) * INV_EPSLN2;
                de = xeta[j] - ye; dp = xphi[j] - yp;
                kt = -sqrtf(de * de + dp * dp + EPS_F) * INV_EPSLN2;
            }
            KU(s) = ku;
            KT(s) = kt;
        }
    }
    if (tid < NP) {
        const float z = (tid < N) ? 0.f : NEGBIG;   // pads stay NEGBIG in log phase
        uu[tid] = z; vv[tid] = z;
    }
    __syncthreads();

    // ---- warm-up: iterations 1..WARM, exact two-pass LSE in log2 domain ----
    for (int it = 0; it < WARM; ++it) {
        {   // u-pass
            const float4* vp = (const float4*)&vv[q * QUART];
            f2 m2 = {-3e38f, -3e38f};
            #pragma unroll
            for (int s = 0; s < QUADS; ++s) {      // pk_add + pk_max sweep
                F4P v4; v4.v = vp[s];
                m2 = F2MAX(m2, v4.h[0] + Ku[2*s]);
                m2 = F2MAX(m2, v4.h[1] + Ku[2*s+1]);
            }
            float mx = quad_max(fmaxf(m2[0], m2[1]));
            float s0 = 0.f, s1 = 0.f, s2 = 0.f, s3 = 0.f;
            #pragma unroll
            for (int s = 0; s < QUADS; ++s) {
                F4P v4; v4.v = vp[s];
                s0 += FEXP2(v4.f[0] + KU(4*s)   - mx);
                s1 += FEXP2(v4.f[1] + KU(4*s+1) - mx);
                s2 += FEXP2(v4.f[2] + KU(4*s+2) - mx);
                s3 += FEXP2(v4.f[3] + KU(4*s+3) - mx);
            }
            float ss = quad_sum((s0 + s1) + (s2 + s3));
            if (writer) uu[r] = l2a[r] - (mx + FLOG2(fmaxf(ss, 1e-37f)));
        }
        __syncthreads();
        {   // v-pass
            const float4* up = (const float4*)&uu[q * QUART];
            f2 m2 = {-3e38f, -3e38f};
            #pragma unroll
            for (int s = 0; s < QUADS; ++s) {
                F4P u4; u4.v = up[s];
                m2 = F2MAX(m2, u4.h[0] + Kt[2*s]);
                m2 = F2MAX(m2, u4.h[1] + Kt[2*s+1]);
            }
            float mx = quad_max(fmaxf(m2[0], m2[1]));
            float s0 = 0.f, s1 = 0.f, s2 = 0.f, s3 = 0.f;
            #pragma unroll
            for (int s = 0; s < QUADS; ++s) {
                F4P u4; u4.v = up[s];
                s0 += FEXP2(u4.f[0] + KT(4*s)   - mx);
                s1 += FEXP2(u4.f[1] + KT(4*s+1) - mx);
                s2 += FEXP2(u4.f[2] + KT(4*s+2) - mx);
                s3 += FEXP2(u4.f[3] + KT(4*s+3) - mx);
            }
            float ss = quad_sum((s0 + s1) + (s2 + s3));
            if (writer) vv[r] = l2b[r] - (mx + FLOG2(fmaxf(ss, 1e-37f)));
        }
        __syncthreads();
    }

    // ---- FOLD: iteration WARM+1 done exactly, building linear anchors ----
    //   Ku[s] = exp2(nK + v5_j - mu_r), mu_r fresh  -> row max == 1
    //   am = ss6 (linear row sum), fin = a_r / ss6
    //   Kt[s] = exp2(nK^T + u6_j - mv_c), mv_c fresh -> col max == 1
    //   bm = Vhat6 * ssv6 ; LDS switches to linear Uhat/Vhat
    float am, bm, fin, Vh6;
    {   // u-update (exact, fresh max) + Ku' anchor
        const float4* vp = (const float4*)&vv[q * QUART];
        f2 m2 = {-3e38f, -3e38f};
        #pragma unroll
        for (int s = 0; s < QUADS; ++s) {
            F4P v4; v4.v = vp[s];
            m2 = F2MAX(m2, v4.h[0] + Ku[2*s]);
            m2 = F2MAX(m2, v4.h[1] + Ku[2*s+1]);
        }
        float mx = quad_max(fmaxf(m2[0], m2[1]));
        float s0 = 0.f, s1 = 0.f, s2 = 0.f, s3 = 0.f;
        #pragma unroll
        for (int s = 0; s < QUADS; ++s) {
            F4P v4; v4.v = vp[s];
            KU(4*s)   = FEXP2(v4.f[0] + KU(4*s)   - mx);
            KU(4*s+1) = FEXP2(v4.f[1] + KU(4*s+1) - mx);
            KU(4*s+2) = FEXP2(v4.f[2] + KU(4*s+2) - mx);
            KU(4*s+3) = FEXP2(v4.f[3] + KU(4*s+3) - mx);
            s0 += KU(4*s); s1 += KU(4*s+1); s2 += KU(4*s+2); s3 += KU(4*s+3);
        }
        float ss = quad_sum((s0 + s1) + (s2 + s3));   // ss6 >= 1 (argmax term == 1)
        am  = ss;                              // exp2(l2a - mu - u6) == ss6
        fin = FEXP2(l2a[r]) * FRCP(ss);        // exp2(u6 + mu) == a_r / ss6
        if (writer) uu[r] = l2a[r] - (mx + FLOG2(ss));   // u6 (log2, temporary)
    }
    __syncthreads();
    {   // v-update (exact) + Kt' anchor
        const float4* up = (const float4*)&uu[q * QUART];
        f2 m2 = {-3e38f, -3e38f};
        #pragma unroll
        for (int s = 0; s < QUADS; ++s) {
            F4P u4; u4.v = up[s];
            m2 = F2MAX(m2, u4.h[0] + Kt[2*s]);
            m2 = F2MAX(m2, u4.h[1] + Kt[2*s+1]);
        }
        float mx = quad_max(fmaxf(m2[0], m2[1]));
        float s0 = 0.f, s1 = 0.f, s2 = 0.f, s3 = 0.f;
        #pragma unroll
        for (int s = 0; s < QUADS; ++s) {
            F4P u4; u4.v = up[s];
            KT(4*s)   = FEXP2(u4.f[0] + KT(4*s)   - mx);
            KT(4*s+1) = FEXP2(u4.f[1] + KT(4*s+1) - mx);
            KT(4*s+2) = FEXP2(u4.f[2] + KT(4*s+2) - mx);
            KT(4*s+3) = FEXP2(u4.f[3] + KT(4*s+3) - mx);
            s0 += KT(4*s); s1 += KT(4*s+1); s2 += KT(4*s+2); s3 += KT(4*s+3);
        }
        float ssv = quad_sum((s0 + s1) + (s2 + s3));  // ssv6 >= 1
        const float v5r = vv[r];              // old (log) anchor of this column
        float t = l2b[r] - (mx + FLOG2(ssv)) - v5r;   // v6 - v5
        t = fminf(t, 100.f);                  // overflow guard (renorm re-anchors)
        Vh6 = FEXP2(t);
        bm  = Vh6 * ssv;                      // exp2(l2b - mv - v5)
    }
    __syncthreads();                          // all reads of uu (u6) / vv (v5) done
    if (writer) { uu[r] = 1.0f; vv[r] = Vh6; }
    if (tid >= N && tid < NP) { uu[tid] = 0.f; vv[tid] = 0.f; }  // pads: exact 0
    __syncthreads();

    // ---- steady state: packed-f32 fma mat-vec; renorm every 16 (exp2-free);
    //      early exit once the renormalized iterates reach f32 fixed point ----
    for (int it = WARM + 1; it < ITERS; ++it) {
        {   // u-pass: ss = Ku . Vhat ; Uhat = am/ss       (20 × v_pk_fma_f32)
            const float4* vp = (const float4*)&vv[q * QUART];
            f2 a0 = {0.f, 0.f}, a1 = {0.f, 0.f};
            #pragma unroll
            for (int s = 0; s < QUADS; ++s) {
                F4P v4; v4.v = vp[s];
                a0 += v4.h[0] * Ku[2*s];
                a1 += v4.h[1] * Ku[2*s+1];
            }
            float ss = quad_sum((a0[0] + a1[0]) + (a0[1] + a1[1]));
            if (writer) uu[r] = fminf(am * FRCP(fmaxf(ss, 1e-30f)), 1e30f);
        }
        __syncthreads();
        {   // v-pass: ssv = Kt . Uhat ; Vhat = bm/ssv
            const float4* up = (const float4*)&uu[q * QUART];
            f2 a0 = {0.f, 0.f}, a1 = {0.f, 0.f};
            #pragma unroll
            for (int s = 0; s < QUADS; ++s) {
                F4P u4; u4.v = up[s];
                a0 += u4.h[0] * Kt[2*s];
                a1 += u4.h[1] * Kt[2*s+1];
            }
            float ss = quad_sum((a0[0] + a1[0]) + (a0[1] + a1[1]));
            if (writer) vv[r] = fminf(bm * FRCP(fmaxf(ss, 1e-30f)), 1e30f);
        }
        __syncthreads();
        if (((it - WARM - 1) & 15) == 15) {
            // ---- renorm: absorb Uhat/Vhat into kernels, reset to 1 ----
            const float4* vp = (const float4*)&vv[q * QUART];
            float M = 0.f;
            #pragma unroll
            for (int s = 0; s < QUADS; ++s) {
                F4P v4; v4.v = vp[s];
                Ku[2*s]   *= v4.h[0];          // v_pk_mul_f32
                Ku[2*s+1] *= v4.h[1];
                M = fmaxf(M, fmaxf(fmaxf(Ku[2*s][0], Ku[2*s][1]),
                                   fmaxf(Ku[2*s+1][0], Ku[2*s+1][1])));
            }
            M = quad_max(M);
            M = fmaxf(M, 1e-30f);
            const float rM = FRCP(M);
            const f2 rM2 = {rM, rM};
            #pragma unroll
            for (int i = 0; i < QUART / 2; ++i) Ku[i] *= rM2;   // row max -> 1

            const float4* up = (const float4*)&uu[q * QUART];
            float Mv = 0.f;
            #pragma unroll
            for (int s = 0; s < QUADS; ++s) {
                F4P u4; u4.v = up[s];
                Kt[2*s]   *= u4.h[0];
                Kt[2*s+1] *= u4.h[1];
                Mv = fmaxf(Mv, fmaxf(fmaxf(Kt[2*s][0], Kt[2*s][1]),
                                     fmaxf(Kt[2*s+1][0], Kt[2*s+1][1])));
            }
            Mv = quad_max(Mv);
            Mv = fmaxf(Mv, 1e-30f);
            const float rMv = FRCP(Mv);
            const f2 rMv2 = {rMv, rMv};
            #pragma unroll
            for (int i = 0; i < QUART / 2; ++i) Kt[i] *= rMv2;  // col max -> 1

            const float Uh = uu[r], Vh = vv[r];
            am  = fminf(am * rM  * FRCP(fmaxf(Uh, 1e-30f)), 1e30f);
            bm  = fminf(bm * rMv * FRCP(fmaxf(Vh, 1e-30f)), 1e30f);
            fin = fminf(fin * M * Uh, 1e30f);
            // converged when renormalized iterates are at an f32 fixed point:
            // remaining iterations would be no-ops (geometric-rate bound).
            const int conv = (fabsf(Uh - 1.0f) < CONV_TOL) &
                             (fabsf(Vh - 1.0f) < CONV_TOL);
            __syncthreads();                   // all folds read uu/vv
            if (writer) { uu[r] = 1.0f; vv[r] = 1.0f; }
            if (__syncthreads_and(conv)) break;   // barrier + block-wide vote
        }
    }

    // ---- EMD: P = fin * Uhat[r] * Vhat[j] * Ku[r][j]; sum P * C ----
    float acc = 0.f;
    if (act) {
        const float u2 = fin * uu[r];
        const float xe = xeta[r], xp = xphi[r];
        const float4* vp = (const float4*)&vv[q * QUART];
        #pragma unroll
        for (int s = 0; s < QUADS; ++s) {
            F4P v4; v4.v = vp[s];
            #pragma unroll
            for (int k = 0; k < 4; ++k) {
                const int j = q * QUART + 4 * s + k;
                if (j < N) {
                    const float de = xe - yeta[j];
                    const float dp = xp - yphi[j];
                    const float C = sqrtf(de * de + dp * dp + EPS_F);
                    acc += u2 * v4.f[k] * KU(4 * s + k) * C;
                }
            }
        }
    }
    if (!act) acc = 0.f;
    acc = blockReduceSum(acc, red);
    if (tid == 0) atomicAdd(out, acc);
}

extern "C" void kernel_launch(void* const* d_in, const int* in_sizes, int n_in,
                              void* d_out, int out_size, void* d_ws, size_t ws_size,
                              hipStream_t stream) {
    const float* pr = (const float*)d_in[0];
    const float* pt = (const float*)d_in[1];
    float* out = (float*)d_out;
    const int B = in_sizes[0] / (N * 3);
    hipMemsetAsync(d_out, 0, sizeof(float) * out_size, stream);
    hipLaunchKernelGGL(emd_kernel, dim3(B), dim3(BLOCK), 0, stream, pr, pt, out);
}

// Round 11
// 843.413 us; speedup vs baseline: 1.0585x; 1.0585x over previous
//
#include <hip/hip_runtime.h>
#include <math.h>

#define N 150
#define NP 160            // padded: 4 workers × 40 cols, float4-aligned
#define QUART 40
#define QUADS 10          // QUART/4
#define BLOCK 640         // 10 waves; 4 workers per row (600 active)
#define ITERS 100
#define WARM 5

#define PI_F 3.14159265358979323846f
#define TWO_PI_F 6.28318530717958647692f
#define EPS_F 1e-16f
// SINKHORN_EPS = 0.05 ; base-2 log domain: K = C/(eps*ln2)
#define EPSLN2 0.03465735902799726f
#define INV_EPSLN2 28.853900817779268f
#define NEGBIG -1e30f

#if __has_builtin(__builtin_amdgcn_exp2f)
#define FEXP2(x) __builtin_amdgcn_exp2f(x)
#else
#define FEXP2(x) exp2f(x)
#endif
#if __has_builtin(__builtin_amdgcn_logf)
#define FLOG2(x) __builtin_amdgcn_logf(x)
#else
#define FLOG2(x) log2f(x)
#endif
#if __has_builtin(__builtin_amdgcn_rcpf)
#define FRCP(x) __builtin_amdgcn_rcpf(x)
#else
#define FRCP(x) (1.0f / (x))
#endif

// packed 2×f32 lane for v_pk_fma_f32 / v_pk_mul_f32 / v_pk_add_f32 emission
typedef float f2 __attribute__((ext_vector_type(2)));
union F4P { float4 v; f2 h[2]; float f[4]; };

#if __has_builtin(__builtin_elementwise_max)
#define F2MAX(a, b) __builtin_elementwise_max((a), (b))
#else
__device__ __forceinline__ f2 f2max_fb(f2 a, f2 b) {
    f2 r; r[0] = fmaxf(a[0], b[0]); r[1] = fmaxf(a[1], b[1]); return r;
}
#define F2MAX(a, b) f2max_fb((a), (b))
#endif

// compile-time element access into the f2-packed K arrays
#define KU(e) Ku[(e) >> 1][(e) & 1]
#define KT(e) Kt[(e) >> 1][(e) & 1]

// ---- DPP helpers: VALU-pipe cross-lane, no LDS traffic ----
// 0xB1 quad_perm xor1 ; 0x4E quad_perm xor2
__device__ __forceinline__ float dpp_xor1(float x) {
    return __int_as_float(__builtin_amdgcn_update_dpp(
        0, __float_as_int(x), 0xB1, 0xF, 0xF, true));
}
__device__ __forceinline__ float dpp_xor2(float x) {
    return __int_as_float(__builtin_amdgcn_update_dpp(
        0, __float_as_int(x), 0x4E, 0xF, 0xF, true));
}
__device__ __forceinline__ float quad_sum(float x) {
    x += dpp_xor1(x); x += dpp_xor2(x); return x;
}
__device__ __forceinline__ float quad_max(float x) {
    x = fmaxf(x, dpp_xor1(x)); x = fmaxf(x, dpp_xor2(x)); return x;
}

__device__ __forceinline__ float blockReduceSum(float v, float* red) {
    for (int o = 32; o > 0; o >>= 1) v += __shfl_down(v, o, 64);
    const int lane = threadIdx.x & 63;
    const int wv = threadIdx.x >> 6;
    __syncthreads();
    if (lane == 0) red[wv] = v;
    __syncthreads();
    float s = 0.f;
    #pragma unroll
    for (int i = 0; i < BLOCK / 64; ++i) s += red[i];
    return s;
}

// 3-component fused block reduction (bit-identical per component)
__device__ __forceinline__ void blockReduceSum3(
    float& x, float& y, float& z, float* red)
{
    for (int o = 32; o > 0; o >>= 1) {
        x += __shfl_down(x, o, 64);
        y += __shfl_down(y, o, 64);
        z += __shfl_down(z, o, 64);
    }
    const int lane = threadIdx.x & 63;
    const int wv = threadIdx.x >> 6;
    __syncthreads();
    if (lane == 0) { red[wv] = x; red[wv + 16] = y; red[wv + 32] = z; }
    __syncthreads();
    float sx = 0.f, sy = 0.f, sz = 0.f;
    #pragma unroll
    for (int i = 0; i < BLOCK / 64; ++i) {
        sx += red[i]; sy += red[i + 16]; sz += red[i + 32];
    }
    x = sx; y = sy; z = sz;
}

__global__ __launch_bounds__(BLOCK, 2) void emd_kernel(
    const float* __restrict__ p_recons,
    const float* __restrict__ p_target,
    float* __restrict__ out)
{
    __shared__ float xeta[N], xphi[N], yeta[N], yphi[N];
    __shared__ float l2a[N], l2b[N];
    __shared__ __align__(16) float uu[NP];
    __shared__ __align__(16) float vv[NP];
    __shared__ float red[48];

    const int b = blockIdx.x;
    const int tid = threadIdx.x;

    // ---- coordinate transform (both clouds) ----
    for (int c = 0; c < 2; ++c) {
        const float* P = (c == 0 ? p_recons : p_target) + (size_t)b * (N * 3);
        float px = 0.f, py = 0.f, pz = 0.f;
        if (tid < N) {
            px = P[tid * 3 + 0];
            py = P[tid * 3 + 1];
            pz = P[tid * 3 + 2];
        }
        float jx = px, jy = py, jz = pz;
        blockReduceSum3(jx, jy, jz, red);
        const float jpt  = sqrtf(jx * jx + jy * jy + EPS_F);
        const float jphi = atan2f(jy + EPS_F, jx + EPS_F);
        const float jeta = asinhf(jz / (jpt + EPS_F));

        float ptrel = 0.f, erel = 0.f, prel = 0.f;
        if (tid < N) {
            const float pt  = sqrtf(px * px + py * py + EPS_F);
            const float phi = atan2f(py + EPS_F, px + EPS_F);
            const float eta = asinhf(pz / (pt + EPS_F));
            erel = eta - jeta;
            float d = phi - jphi + PI_F;
            d = fmodf(d, TWO_PI_F);            // JAX % is floor-mod
            if (d < 0.f) d += TWO_PI_F;
            prel = d - PI_F;
            ptrel = pt / (jpt + EPS_F);
        }
        const float spt = blockReduceSum(ptrel, red);
        if (tid < N) {
            const float aa = ptrel / (spt + EPS_F);
            if (c == 0) { xeta[tid] = erel; xphi[tid] = prel; l2a[tid] = FLOG2(aa + EPS_F); }
            else        { yeta[tid] = erel; yphi[tid] = prel; l2b[tid] = FLOG2(aa + EPS_F); }
        }
    }
    __syncthreads();

    // ---- register-resident -K slices (log2 domain): 4 workers/row, 40 cols ----
    const int r = (tid >> 2) < N ? (tid >> 2) : (N - 1);   // clamped for uniform exec
    const int q = tid & 3;
    const bool writer = (q == 0) && ((tid >> 2) < N);
    const bool act = (tid >> 2) < N;

    f2 Ku[QUART / 2];   // log: -K[r][q*40+s] ; after fold: linear Ku'
    f2 Kt[QUART / 2];   // log: -K[q*40+s][r] ; after fold: linear Kt'
    {
        const float xe = xeta[r], xp = xphi[r];
        const float ye = yeta[r], yp = yphi[r];
        #pragma unroll
        for (int s = 0; s < QUART; ++s) {
            const int j = q * QUART + s;
            float ku = NEGBIG, kt = NEGBIG;       // pads never contribute
            if (j < N) {
                float de = xe - yeta[j], dp = xp - yphi[j];
                ku = -sqrtf(de * de + dp * dp + EPS_F) * INV_EPSLN2;
                de = xeta[j] - ye; dp = xphi[j] - yp;
                kt = -sqrtf(de * de + dp * dp + EPS_F) * INV_EPSLN2;
            }
            KU(s) = ku;
            KT(s) = kt;
        }
    }
    if (tid < NP) {
        const float z = (tid < N) ? 0.f : NEGBIG;   // pads stay NEGBIG in log phase
        uu[tid] = z; vv[tid] = z;
    }
    __syncthreads();

    // ---- warm-up: iterations 1..WARM, exact two-pass LSE in log2 domain ----
    for (int it = 0; it < WARM; ++it) {
        {   // u-pass
            const float4* vp = (const float4*)&vv[q * QUART];
            f2 m2 = {-3e38f, -3e38f};
            #pragma unroll
            for (int s = 0; s < QUADS; ++s) {      // pk_add + pk_max sweep
                F4P v4; v4.v = vp[s];
                m2 = F2MAX(m2, v4.h[0] + Ku[2*s]);
                m2 = F2MAX(m2, v4.h[1] + Ku[2*s+1]);
            }
            float mx = quad_max(fmaxf(m2[0], m2[1]));
            float s0 = 0.f, s1 = 0.f, s2 = 0.f, s3 = 0.f;
            #pragma unroll
            for (int s = 0; s < QUADS; ++s) {
                F4P v4; v4.v = vp[s];
                s0 += FEXP2(v4.f[0] + KU(4*s)   - mx);
                s1 += FEXP2(v4.f[1] + KU(4*s+1) - mx);
                s2 += FEXP2(v4.f[2] + KU(4*s+2) - mx);
                s3 += FEXP2(v4.f[3] + KU(4*s+3) - mx);
            }
            float ss = quad_sum((s0 + s1) + (s2 + s3));
            if (writer) uu[r] = l2a[r] - (mx + FLOG2(fmaxf(ss, 1e-37f)));
        }
        __syncthreads();
        {   // v-pass
            const float4* up = (const float4*)&uu[q * QUART];
            f2 m2 = {-3e38f, -3e38f};
            #pragma unroll
            for (int s = 0; s < QUADS; ++s) {
                F4P u4; u4.v = up[s];
                m2 = F2MAX(m2, u4.h[0] + Kt[2*s]);
                m2 = F2MAX(m2, u4.h[1] + Kt[2*s+1]);
            }
            float mx = quad_max(fmaxf(m2[0], m2[1]));
            float s0 = 0.f, s1 = 0.f, s2 = 0.f, s3 = 0.f;
            #pragma unroll
            for (int s = 0; s < QUADS; ++s) {
                F4P u4; u4.v = up[s];
                s0 += FEXP2(u4.f[0] + KT(4*s)   - mx);
                s1 += FEXP2(u4.f[1] + KT(4*s+1) - mx);
                s2 += FEXP2(u4.f[2] + KT(4*s+2) - mx);
                s3 += FEXP2(u4.f[3] + KT(4*s+3) - mx);
            }
            float ss = quad_sum((s0 + s1) + (s2 + s3));
            if (writer) vv[r] = l2b[r] - (mx + FLOG2(fmaxf(ss, 1e-37f)));
        }
        __syncthreads();
    }

    // ---- FOLD: iteration WARM+1 done exactly, building linear anchors ----
    //   Ku[s] = exp2(nK + v5_j - mu_r), mu_r fresh  -> row max == 1
    //   am = ss6 (linear row sum), fin = a_r / ss6
    //   Kt[s] = exp2(nK^T + u6_j - mv_c), mv_c fresh -> col max == 1
    //   bm = Vhat6 * ssv6 ; LDS switches to linear Uhat/Vhat
    float am, bm, fin, Vh6;
    {   // u-update (exact, fresh max) + Ku' anchor
        const float4* vp = (const float4*)&vv[q * QUART];
        f2 m2 = {-3e38f, -3e38f};
        #pragma unroll
        for (int s = 0; s < QUADS; ++s) {
            F4P v4; v4.v = vp[s];
            m2 = F2MAX(m2, v4.h[0] + Ku[2*s]);
            m2 = F2MAX(m2, v4.h[1] + Ku[2*s+1]);
        }
        float mx = quad_max(fmaxf(m2[0], m2[1]));
        float s0 = 0.f, s1 = 0.f, s2 = 0.f, s3 = 0.f;
        #pragma unroll
        for (int s = 0; s < QUADS; ++s) {
            F4P v4; v4.v = vp[s];
            KU(4*s)   = FEXP2(v4.f[0] + KU(4*s)   - mx);
            KU(4*s+1) = FEXP2(v4.f[1] + KU(4*s+1) - mx);
            KU(4*s+2) = FEXP2(v4.f[2] + KU(4*s+2) - mx);
            KU(4*s+3) = FEXP2(v4.f[3] + KU(4*s+3) - mx);
            s0 += KU(4*s); s1 += KU(4*s+1); s2 += KU(4*s+2); s3 += KU(4*s+3);
        }
        float ss = quad_sum((s0 + s1) + (s2 + s3));   // ss6 >= 1 (argmax term == 1)
        am  = ss;                              // exp2(l2a - mu - u6) == ss6
        fin = FEXP2(l2a[r]) * FRCP(ss);        // exp2(u6 + mu) == a_r / ss6
        if (writer) uu[r] = l2a[r] - (mx + FLOG2(ss));   // u6 (log2, temporary)
    }
    __syncthreads();
    {   // v-update (exact) + Kt' anchor
        const float4* up = (const float4*)&uu[q * QUART];
        f2 m2 = {-3e38f, -3e38f};
        #pragma unroll
        for (int s = 0; s < QUADS; ++s) {
            F4P u4; u4.v = up[s];
            m2 = F2MAX(m2, u4.h[0] + Kt[2*s]);
            m2 = F2MAX(m2, u4.h[1] + Kt[2*s+1]);
        }
        float mx = quad_max(fmaxf(m2[0], m2[1]));
        float s0 = 0.f, s1 = 0.f, s2 = 0.f, s3 = 0.f;
        #pragma unroll
        for (int s = 0; s < QUADS; ++s) {
            F4P u4; u4.v = up[s];
            KT(4*s)   = FEXP2(u4.f[0] + KT(4*s)   - mx);
            KT(4*s+1) = FEXP2(u4.f[1] + KT(4*s+1) - mx);
            KT(4*s+2) = FEXP2(u4.f[2] + KT(4*s+2) - mx);
            KT(4*s+3) = FEXP2(u4.f[3] + KT(4*s+3) - mx);
            s0 += KT(4*s); s1 += KT(4*s+1); s2 += KT(4*s+2); s3 += KT(4*s+3);
        }
        float ssv = quad_sum((s0 + s1) + (s2 + s3));  // ssv6 >= 1
        const float v5r = vv[r];              // old (log) anchor of this column
        float t = l2b[r] - (mx + FLOG2(ssv)) - v5r;   // v6 - v5
        t = fminf(t, 100.f);                  // overflow guard (renorm re-anchors)
        Vh6 = FEXP2(t);
        bm  = Vh6 * ssv;                      // exp2(l2b - mv - v5)
    }
    __syncthreads();                          // all reads of uu (u6) / vv (v5) done
    if (writer) { uu[r] = 1.0f; vv[r] = Vh6; }
    if (tid >= N && tid < NP) { uu[tid] = 0.f; vv[tid] = 0.f; }  // pads: exact 0
    __syncthreads();

    // ---- steady state: packed-f32 fma mat-vec; renorm every 32 (exp2-free).
    //      Drift bound: round-0 kernel ran 95 iters with NO re-anchor and a
    //      +100 log2 clamp that never engaged -> 32-iter windows are safe. ----
    for (int it = WARM + 1; it < ITERS; ++it) {
        {   // u-pass: ss = Ku . Vhat ; Uhat = am/ss       (20 × v_pk_fma_f32)
            const float4* vp = (const float4*)&vv[q * QUART];
            f2 a0 = {0.f, 0.f}, a1 = {0.f, 0.f};
            #pragma unroll
            for (int s = 0; s < QUADS; ++s) {
                F4P v4; v4.v = vp[s];
                a0 += v4.h[0] * Ku[2*s];
                a1 += v4.h[1] * Ku[2*s+1];
            }
            float ss = quad_sum((a0[0] + a1[0]) + (a0[1] + a1[1]));
            if (writer) uu[r] = fminf(am * FRCP(fmaxf(ss, 1e-30f)), 1e30f);
        }
        __syncthreads();
        {   // v-pass: ssv = Kt . Uhat ; Vhat = bm/ssv
            const float4* up = (const float4*)&uu[q * QUART];
            f2 a0 = {0.f, 0.f}, a1 = {0.f, 0.f};
            #pragma unroll
            for (int s = 0; s < QUADS; ++s) {
                F4P u4; u4.v = up[s];
                a0 += u4.h[0] * Kt[2*s];
                a1 += u4.h[1] * Kt[2*s+1];
            }
            float ss = quad_sum((a0[0] + a1[0]) + (a0[1] + a1[1]));
            if (writer) vv[r] = fminf(bm * FRCP(fmaxf(ss, 1e-30f)), 1e30f);
        }
        __syncthreads();
        if (((it - WARM - 1) & 31) == 31) {
            // ---- renorm: absorb Uhat/Vhat into kernels, reset to 1 ----
            const float4* vp = (const float4*)&vv[q * QUART];
            float M = 0.f;
            #pragma unroll
            for (int s = 0; s < QUADS; ++s) {
                F4P v4; v4.v = vp[s];
                Ku[2*s]   *= v4.h[0];          // v_pk_mul_f32
                Ku[2*s+1] *= v4.h[1];
                M = fmaxf(M, fmaxf(fmaxf(Ku[2*s][0], Ku[2*s][1]),
                                   fmaxf(Ku[2*s+1][0], Ku[2*s+1][1])));
            }
            M = quad_max(M);
            M = fmaxf(M, 1e-30f);
            const float rM = FRCP(M);
            const f2 rM2 = {rM, rM};
            #pragma unroll
            for (int i = 0; i < QUART / 2; ++i) Ku[i] *= rM2;   // row max -> 1

            const float4* up = (const float4*)&uu[q * QUART];
            float Mv = 0.f;
            #pragma unroll
            for (int s = 0; s < QUADS; ++s) {
                F4P u4; u4.v = up[s];
                Kt[2*s]   *= u4.h[0];
                Kt[2*s+1] *= u4.h[1];
                Mv = fmaxf(Mv, fmaxf(fmaxf(Kt[2*s][0], Kt[2*s][1]),
                                     fmaxf(Kt[2*s+1][0], Kt[2*s+1][1])));
            }
            Mv = quad_max(Mv);
            Mv = fmaxf(Mv, 1e-30f);
            const float rMv = FRCP(Mv);
            const f2 rMv2 = {rMv, rMv};
            #pragma unroll
            for (int i = 0; i < QUART / 2; ++i) Kt[i] *= rMv2;  // col max -> 1

            const float Uh = uu[r], Vh = vv[r];
            am  = fminf(am * rM  * FRCP(fmaxf(Uh, 1e-30f)), 1e30f);
            bm  = fminf(bm * rMv * FRCP(fmaxf(Vh, 1e-30f)), 1e30f);
            fin = fminf(fin * M * Uh, 1e30f);
            __syncthreads();                   // all folds read uu/vv
            if (writer) { uu[r] = 1.0f; vv[r] = 1.0f; }
            __syncthreads();
        }
    }

    // ---- EMD: P = fin * Uhat[r] * Vhat[j] * Ku[r][j]; sum P * C ----
    float acc = 0.f;
    if (act) {
        const float u2 = fin * uu[r];
        const float xe = xeta[r], xp = xphi[r];
        const float4* vp = (const float4*)&vv[q * QUART];
        #pragma unroll
        for (int s = 0; s < QUADS; ++s) {
            F4P v4; v4.v = vp[s];
            #pragma unroll
            for (int k = 0; k < 4; ++k) {
                const int j = q * QUART + 4 * s + k;
                if (j < N) {
                    const float de = xe - yeta[j];
                    const float dp = xp - yphi[j];
                    const float C = sqrtf(de * de + dp * dp + EPS_F);
                    acc += u2 * v4.f[k] * KU(4 * s + k) * C;
                }
            }
        }
    }
    if (!act) acc = 0.f;
    acc = blockReduceSum(acc, red);
    if (tid == 0) atomicAdd(out, acc);
}

extern "C" void kernel_launch(void* const* d_in, const int* in_sizes, int n_in,
                              void* d_out, int out_size, void* d_ws, size_t ws_size,
                              hipStream_t stream) {
    const float* pr = (const float*)d_in[0];
    const float* pt = (const float*)d_in[1];
    float* out = (float*)d_out;
    const int B = in_sizes[0] / (N * 3);
    hipMemsetAsync(d_out, 0, sizeof(float) * out_size, stream);
    hipLaunchKernelGGL(emd_kernel, dim3(B), dim3(BLOCK), 0, stream, pr, pt, out);
}